// Round 3
// baseline (186.572 us; speedup 1.0000x reference)
//
#include <hip/hip_runtime.h>

#define STEPS   2000
#define DT_F    0.001f
#define EPS_F   1e-6f
#define MAXT_F  2.0f
#define CHUNK   16
#define NCHUNK  (STEPS / CHUNK)   // 125
#define DPRE    4                 // prefetch distance in chunks (16 dwordx4 in flight)

// Cooperative wide load of one 16-row x 64-col chunk for this wave:
// instruction m (0..3), lane l covers row m*4+(l>>4), cols (l&15)*4 .. +3.
// Chunk index clamped so the tail is branch-free (redundant tail re-reads hit L2).
#define LOADG(GB, c_) do {                                                    \
    const int cc = ((c_) < NCHUNK) ? (c_) : (NCHUNK - 1);                     \
    const float* bp = wpl + (size_t)(cc * CHUNK) * stride;                    \
    _Pragma("unroll")                                                         \
    for (int m = 0; m < 4; ++m)                                               \
        GB[m] = *(const float4*)(bp + (size_t)(4 * m) * stride);              \
} while (0)

// One chunk: spill the register tile to wave-private LDS, immediately issue the
// chunk-(cb+DPRE) prefetch into the same registers, then consume 16 steps from
// LDS. Inner step is branchless: 1 abs-compare + 2 cndmask latches.
// dv recurrence keeps the exact reference rounding: ((dv + drift*DT) + ns*nz),
// separate mul/add, no FMA contraction.
#define DO_CHUNK(GB, cb) do {                                                 \
    _Pragma("unroll")                                                         \
    for (int m = 0; m < 4; ++m)                                               \
        *(float4*)(&lds[wv][m * 4 + lrow][lcol]) = GB[m];                     \
    LOADG(GB, (cb) + DPRE);                                                   \
    _Pragma("unroll")                                                         \
    for (int k = 0; k < CHUNK; ++k) {                                         \
        const float nz = lds[wv][k][lane];                                    \
        dv = __fadd_rn(__fadd_rn(dv, drift_dt), __fmul_rn(nscale, nz));       \
        const bool hit = act && (__builtin_fabsf(dv) >= a_hi);                \
        t_hit  = hit ? ((cb) * CHUNK + k) : t_hit;                            \
        dv_hit = hit ? dv : dv_hit;                                           \
        act    = act && !hit;                                                 \
    }                                                                         \
} while (0)

__global__ __launch_bounds__(256, 1) void ddm_sim_kernel(
    const float* __restrict__ x,
    const float* __restrict__ noise,
    const float* __restrict__ p_a,
    const float* __restrict__ p_z,
    const float* __restrict__ p_ndt,
    const float* __restrict__ p_dg,
    float* __restrict__ out,   // [0,n) = pred_rt, [n,2n) = pred_choice
    int n)
{
    // wave-private staging tiles: 4 waves x 16 rows x 64 cols x f32 = 16 KB.
    // Each wave touches only lds[wv] -> no __syncthreads ever.
    __shared__ __align__(16) float lds[4][CHUNK][64];

    const int tid   = threadIdx.x;
    const int wv    = tid >> 6;
    const int lane  = tid & 63;
    const int wbase = blockIdx.x * 256 + wv * 64;  // wave's first trial
    if (wbase >= n) return;
    const int i = wbase + lane;

    const float a   = *p_a;
    const float z   = *p_z;
    const float ndt = *p_ndt;
    const float dg  = *p_dg;

    const float drift_dt = __fmul_rn(__fmul_rn(dg, x[i]), DT_F);
    const float nscale   = __fsqrt_rn(DT_F);     // SIGMA(=1) * sqrt(DT)
    const float a_hi     = __fsub_rn(a, EPS_F);  // a - EPS; fl(EPS-a) == -a_hi (RN symmetry)

    float dv     = __fmul_rn(z, a);
    float dv_hit = 0.0f;
    int   t_hit  = 0;
    bool  act    = true;

    const size_t stride = (size_t)n;
    const int    lrow   = lane >> 4;        // row-in-group 0..3
    const int    lcol   = (lane & 15) * 4;  // float col offset 0..60
    const float* wpl    = noise + wbase + (size_t)lrow * stride + lcol;

    float4 g0[4], g1[4], g2[4], g3[4];
    LOADG(g0, 0);
    LOADG(g1, 1);
    LOADG(g2, 2);
    LOADG(g3, 3);

    int c = 0;
    while (true) {
        DO_CHUNK(g0, c); ++c; if (c >= NCHUNK || !__any(act)) break;
        DO_CHUNK(g1, c); ++c; if (c >= NCHUNK || !__any(act)) break;
        DO_CHUNK(g2, c); ++c; if (c >= NCHUNK || !__any(act)) break;
        DO_CHUNK(g3, c); ++c; if (c >= NCHUNK || !__any(act)) break;
    }

    // epilogue: same pinned op sequence as the reference for rt/choice
    float rt, choice;
    if (act) {
        rt     = __fadd_rn(MAXT_F, ndt);
        choice = 0.5f;
    } else {
        rt     = __fadd_rn(__fmul_rn((float)t_hit, DT_F), ndt);
        choice = (dv_hit > 0.0f) ? 1.0f : 0.0f;   // hit_up <=> dv_hit >= a-eps > 0
    }
    out[i]     = rt;
    out[n + i] = choice;
}

extern "C" void kernel_launch(void* const* d_in, const int* in_sizes, int n_in,
                              void* d_out, int out_size, void* d_ws, size_t ws_size,
                              hipStream_t stream) {
    const float* x     = (const float*)d_in[0];
    const float* noise = (const float*)d_in[1];
    const float* a     = (const float*)d_in[2];
    const float* z     = (const float*)d_in[3];
    const float* ndt   = (const float*)d_in[4];
    const float* dg    = (const float*)d_in[5];
    float* out = (float*)d_out;

    const int n = in_sizes[0];              // 65536 trials (multiple of 256)
    const int block = 256;
    const int grid  = (n + block - 1) / block;
    ddm_sim_kernel<<<grid, block, 0, stream>>>(x, noise, a, z, ndt, dg, out, n);
}

// Round 4
// 91.473 us; speedup vs baseline: 2.0396x; 2.0396x over previous
//
#include <hip/hip_runtime.h>

#define STEPS   2000
#define DT_F    0.001f
#define EPS_F   1e-6f
#define MAXT_F  2.0f
#define CHUNK   8
#define NCHUNK  (STEPS / CHUNK)   // 250
// 8 rotating register buffers -> prefetch distance 7 chunks = 56 outstanding
// dword loads (<= vmcnt cap 63, so the compiler emits precise counted waits;
// R2's 80-deep pipeline was un-encodable and over-waited every chunk).

// Prefetch one chunk (8 noise rows) into a register buffer. Chunk index is
// clamped (tail re-reads last chunk, L2-absorbed) so the load stream is
// branch-free.
#define LOADC(BUF, c_) do {                                                   \
    const int cc = ((c_) < NCHUNK) ? (c_) : (NCHUNK - 1);                     \
    const float* bp = p + (size_t)(cc * CHUNK) * stride;                      \
    _Pragma("unroll")                                                         \
    for (int k = 0; k < CHUNK; ++k) BUF[k] = bp[(size_t)k * stride];          \
} while (0)

// Advance CHUNK steps. Exact reference rounding: dv = ((dv + drift*DT) +
// nscale*nz), separate mul/add, no FMA. Branchless hit latch: single
// abs-compare (fl(EPS-a) == -fl(a-EPS) under RN symmetry, so |dv| >= a-EPS
// is identical to the two-sided test) + 2 cndmasks; rt/choice math deferred
// to the epilogue.
#define STEPC(BUF, cbase) do {                                                \
    _Pragma("unroll")                                                         \
    for (int k = 0; k < CHUNK; ++k) {                                         \
        dv = __fadd_rn(__fadd_rn(dv, drift_dt), __fmul_rn(nscale, BUF[k]));   \
        const bool hit = act && (__builtin_fabsf(dv) >= a_hi);                \
        t_hit  = hit ? ((cbase) * CHUNK + k) : t_hit;                         \
        dv_hit = hit ? dv : dv_hit;                                           \
        act    = act && !hit;                                                 \
    }                                                                         \
} while (0)

__global__ __launch_bounds__(256, 1) void ddm_sim_kernel(
    const float* __restrict__ x,
    const float* __restrict__ noise,
    const float* __restrict__ p_a,
    const float* __restrict__ p_z,
    const float* __restrict__ p_ndt,
    const float* __restrict__ p_dg,
    float* __restrict__ out,   // [0,n) = pred_rt, [n,2n) = pred_choice
    int n)
{
    const int i = blockIdx.x * blockDim.x + threadIdx.x;
    if (i >= n) return;

    const float a   = *p_a;
    const float z   = *p_z;
    const float ndt = *p_ndt;
    const float dg  = *p_dg;

    const float drift_dt = __fmul_rn(__fmul_rn(dg, x[i]), DT_F);
    const float nscale   = __fsqrt_rn(DT_F);     // SIGMA(=1) * sqrt(DT)
    const float a_hi     = __fsub_rn(a, EPS_F);  // a - EPS

    float dv     = __fmul_rn(z, a);
    float dv_hit = 0.0f;
    int   t_hit  = 0;
    bool  act    = true;

    const float* p      = noise + i;
    const size_t stride = (size_t)n;

    float B0[CHUNK], B1[CHUNK], B2[CHUNK], B3[CHUNK],
          B4[CHUNK], B5[CHUNK], B6[CHUNK], B7[CHUNK];

    // prologue: fill pipeline 7 deep (56 loads in flight, 14 KB/wave)
    LOADC(B0, 0);
    LOADC(B1, 1);
    LOADC(B2, 2);
    LOADC(B3, 3);
    LOADC(B4, 4);
    LOADC(B5, 5);
    LOADC(B6, 6);

    int c = 0;
    while (true) {
        LOADC(B7, c + 7); STEPC(B0, c); ++c; if (c >= NCHUNK || !__any(act)) break;
        LOADC(B0, c + 7); STEPC(B1, c); ++c; if (c >= NCHUNK || !__any(act)) break;
        LOADC(B1, c + 7); STEPC(B2, c); ++c; if (c >= NCHUNK || !__any(act)) break;
        LOADC(B2, c + 7); STEPC(B3, c); ++c; if (c >= NCHUNK || !__any(act)) break;
        LOADC(B3, c + 7); STEPC(B4, c); ++c; if (c >= NCHUNK || !__any(act)) break;
        LOADC(B4, c + 7); STEPC(B5, c); ++c; if (c >= NCHUNK || !__any(act)) break;
        LOADC(B5, c + 7); STEPC(B6, c); ++c; if (c >= NCHUNK || !__any(act)) break;
        LOADC(B6, c + 7); STEPC(B7, c); ++c; if (c >= NCHUNK || !__any(act)) break;
    }

    // epilogue: same pinned op sequence as the reference for rt/choice
    float rt, choice;
    if (act) {
        rt     = __fadd_rn(MAXT_F, ndt);
        choice = 0.5f;
    } else {
        rt     = __fadd_rn(__fmul_rn((float)t_hit, DT_F), ndt);
        choice = (dv_hit > 0.0f) ? 1.0f : 0.0f;   // hit_up <=> dv_hit >= a-eps > 0
    }
    out[i]     = rt;
    out[n + i] = choice;
}

extern "C" void kernel_launch(void* const* d_in, const int* in_sizes, int n_in,
                              void* d_out, int out_size, void* d_ws, size_t ws_size,
                              hipStream_t stream) {
    const float* x     = (const float*)d_in[0];
    const float* noise = (const float*)d_in[1];
    const float* a     = (const float*)d_in[2];
    const float* z     = (const float*)d_in[3];
    const float* ndt   = (const float*)d_in[4];
    const float* dg    = (const float*)d_in[5];
    float* out = (float*)d_out;

    const int n = in_sizes[0];              // 65536 trials
    const int block = 256;
    const int grid  = (n + block - 1) / block;
    ddm_sim_kernel<<<grid, block, 0, stream>>>(x, noise, a, z, ndt, dg, out, n);
}

// Round 5
// 88.304 us; speedup vs baseline: 2.1128x; 1.0359x over previous
//
#include <hip/hip_runtime.h>

#define STEPS   2000
#define DT_F    0.001f
#define EPS_F   1e-6f
#define MAXT_F  2.0f
#define CHUNK   8
#define NCHUNK  (STEPS / CHUNK)   // 250
// 8 rotating register buffers -> prefetch distance 7 chunks = ~56 outstanding
// dword loads (inside the 6-bit vmcnt budget -> precise counted waits).
// R5 change vs R4: non-temporal loads (streaming data, zero reuse -- skip L2
// fill/evict overhead). Structure otherwise identical to the verified R4.

#define LOADC(BUF, c_) do {                                                   \
    const int cc = ((c_) < NCHUNK) ? (c_) : (NCHUNK - 1);                     \
    const float* bp = p + (size_t)(cc * CHUNK) * stride;                      \
    _Pragma("unroll")                                                         \
    for (int k = 0; k < CHUNK; ++k)                                           \
        BUF[k] = __builtin_nontemporal_load(bp + (size_t)k * stride);         \
} while (0)

// Exact reference rounding: dv = ((dv + drift*DT) + nscale*nz), separate
// mul/add, no FMA. Branchless hit latch: single abs-compare (fl(EPS-a) ==
// -fl(a-EPS) under RN symmetry -> identical to the two-sided test) + latches.
#define STEPC(BUF, cbase) do {                                                \
    _Pragma("unroll")                                                         \
    for (int k = 0; k < CHUNK; ++k) {                                         \
        dv = __fadd_rn(__fadd_rn(dv, drift_dt), __fmul_rn(nscale, BUF[k]));   \
        const bool hit = act && (__builtin_fabsf(dv) >= a_hi);                \
        t_hit  = hit ? ((cbase) * CHUNK + k) : t_hit;                         \
        dv_hit = hit ? dv : dv_hit;                                           \
        act    = act && !hit;                                                 \
    }                                                                         \
} while (0)

__global__ __launch_bounds__(256, 1) void ddm_sim_kernel(
    const float* __restrict__ x,
    const float* __restrict__ noise,
    const float* __restrict__ p_a,
    const float* __restrict__ p_z,
    const float* __restrict__ p_ndt,
    const float* __restrict__ p_dg,
    float* __restrict__ out,   // [0,n) = pred_rt, [n,2n) = pred_choice
    int n)
{
    const int i = blockIdx.x * blockDim.x + threadIdx.x;
    if (i >= n) return;

    const float a   = *p_a;
    const float z   = *p_z;
    const float ndt = *p_ndt;
    const float dg  = *p_dg;

    const float drift_dt = __fmul_rn(__fmul_rn(dg, x[i]), DT_F);
    const float nscale   = __fsqrt_rn(DT_F);     // SIGMA(=1) * sqrt(DT)
    const float a_hi     = __fsub_rn(a, EPS_F);  // a - EPS

    float dv     = __fmul_rn(z, a);
    float dv_hit = 0.0f;
    int   t_hit  = 0;
    bool  act    = true;

    const float* p      = noise + i;
    const size_t stride = (size_t)n;

    float B0[CHUNK], B1[CHUNK], B2[CHUNK], B3[CHUNK],
          B4[CHUNK], B5[CHUNK], B6[CHUNK], B7[CHUNK];

    // prologue: fill pipeline 7 deep (56 loads in flight, 14 KB/wave)
    LOADC(B0, 0);
    LOADC(B1, 1);
    LOADC(B2, 2);
    LOADC(B3, 3);
    LOADC(B4, 4);
    LOADC(B5, 5);
    LOADC(B6, 6);

    int c = 0;
    while (true) {
        LOADC(B7, c + 7); STEPC(B0, c); ++c; if (c >= NCHUNK || !__any(act)) break;
        LOADC(B0, c + 7); STEPC(B1, c); ++c; if (c >= NCHUNK || !__any(act)) break;
        LOADC(B1, c + 7); STEPC(B2, c); ++c; if (c >= NCHUNK || !__any(act)) break;
        LOADC(B2, c + 7); STEPC(B3, c); ++c; if (c >= NCHUNK || !__any(act)) break;
        LOADC(B3, c + 7); STEPC(B4, c); ++c; if (c >= NCHUNK || !__any(act)) break;
        LOADC(B4, c + 7); STEPC(B5, c); ++c; if (c >= NCHUNK || !__any(act)) break;
        LOADC(B5, c + 7); STEPC(B6, c); ++c; if (c >= NCHUNK || !__any(act)) break;
        LOADC(B6, c + 7); STEPC(B7, c); ++c; if (c >= NCHUNK || !__any(act)) break;
    }

    // epilogue: same pinned op sequence as the reference for rt/choice
    float rt, choice;
    if (act) {
        rt     = __fadd_rn(MAXT_F, ndt);
        choice = 0.5f;
    } else {
        rt     = __fadd_rn(__fmul_rn((float)t_hit, DT_F), ndt);
        choice = (dv_hit > 0.0f) ? 1.0f : 0.0f;   // hit_up <=> dv_hit >= a-eps > 0
    }
    __builtin_nontemporal_store(rt,     out + i);
    __builtin_nontemporal_store(choice, out + n + i);
}

extern "C" void kernel_launch(void* const* d_in, const int* in_sizes, int n_in,
                              void* d_out, int out_size, void* d_ws, size_t ws_size,
                              hipStream_t stream) {
    const float* x     = (const float*)d_in[0];
    const float* noise = (const float*)d_in[1];
    const float* a     = (const float*)d_in[2];
    const float* z     = (const float*)d_in[3];
    const float* ndt   = (const float*)d_in[4];
    const float* dg    = (const float*)d_in[5];
    float* out = (float*)d_out;

    const int n = in_sizes[0];              // 65536 trials
    const int block = 256;
    const int grid  = (n + block - 1) / block;
    ddm_sim_kernel<<<grid, block, 0, stream>>>(x, noise, a, z, ndt, dg, out, n);
}